// Round 2
// baseline (491.951 us; speedup 1.0000x reference)
//
#include <hip/hip_runtime.h>
#include <hip/hip_cooperative_groups.h>

namespace cg = cooperative_groups;

#define EMA_EPS 1e-12f

__device__ __forceinline__ float wave_reduce_sum(float v) {
    #pragma unroll
    for (int off = 32; off > 0; off >>= 1) v += __shfl_xor(v, off, 64);
    return v;
}

// ---------------------------------------------------------------------------
// Fused EMA-LayerNorm, cooperative launch, 3 phases separated by grid.sync():
//   P1: per-row mean/std(ddof=1)       -> ws (mu, sigma)
//   P2: per-batch weighted cumsum scan -> ws (mu_cum, 1/sigma_cum), h_new
//   P3: y = (x - mu_cum)*rs*gamma + beta  (x re-read is L3-warm from P1)
// ---------------------------------------------------------------------------
__global__ __launch_bounds__(256, 4) void ema_fused_kernel(
    const float* __restrict__ x,
    const float* __restrict__ h,
    const float* __restrict__ gamma,
    const float* __restrict__ beta,
    const float* __restrict__ alpha_logit,
    float* __restrict__ out,          // y (B*S*D) then h_new (B*2)
    float* __restrict__ ws,           // 4 * nrows floats
    int B, int S, int d4_shift)       // d4 = D/4 = 1<<d4_shift
{
    cg::grid_group grid = cg::this_grid();
    const int d4     = 1 << d4_shift;
    const int D      = d4 << 2;
    const int nrows  = B * S;

    float* mu_ws = ws;
    float* sg_ws = ws + nrows;
    float* mc_ws = ws + 2 * nrows;
    float* rs_ws = ws + 3 * nrows;

    // ---------------- Phase 1: per-row stats ----------------
    {
        const int gwave  = (int)((blockIdx.x * blockDim.x + threadIdx.x) >> 6);
        const int lane   = threadIdx.x & 63;
        const int nwaves = (int)((gridDim.x * blockDim.x) >> 6);
        for (int row = gwave; row < nrows; row += nwaves) {
            const float4* xr = (const float4*)(x + (size_t)row * (size_t)D);
            float s = 0.f, sq = 0.f;
            for (int c = lane; c < d4; c += 64) {
                float4 a = xr[c];
                s  += a.x + a.y + a.z + a.w;
                sq += a.x*a.x + a.y*a.y + a.z*a.z + a.w*a.w;
            }
            s  = wave_reduce_sum(s);
            sq = wave_reduce_sum(sq);
            if (lane == 0) {
                float mean = s / (float)D;
                float var  = (sq - s * mean) / (float)(D - 1);
                mu_ws[row] = mean;
                sg_ws[row] = sqrtf(fmaxf(var, 0.0f));
            }
        }
    }

    grid.sync();

    // ---------------- Phase 2: per-batch scan (blocks 0..B-1) ----------------
    if ((int)blockIdx.x < B) {
        const int b   = blockIdx.x;
        const int tid = threadIdx.x;
        const int CHUNK = S >> 8;                 // S/256

        const float alpha   = 1.0f / (1.0f + __expf(-alpha_logit[0]));
        const float one_m_a = 1.0f - alpha;
        const float l2a     = __log2f(alpha);

        const float* mub = mu_ws + (size_t)b * S;
        const float* sgb = sg_ws + (size_t)b * S;
        const float h_mu = h[b * 2 + 0];
        const float h_sg = h[b * 2 + 1];

        const int   s0 = tid * CHUNK;
        const float w0 = one_m_a * exp2f((float)s0 * l2a);

        // local sums of w[s]*mu[s], w[s]*sigma[s]
        float lm = 0.f, ls = 0.f;
        {
            float w = w0;
            for (int i = 0; i < CHUNK; ++i) {
                lm += w * mub[s0 + i];
                ls += w * sgb[s0 + i];
                w *= alpha;
            }
        }

        // block exclusive scan of 256 per-thread sums
        const int lane = tid & 63, wid = tid >> 6;
        float im = lm, is = ls;
        #pragma unroll
        for (int off = 1; off < 64; off <<= 1) {
            float tm = __shfl_up(im, off, 64);
            float ts = __shfl_up(is, off, 64);
            if (lane >= off) { im += tm; is += ts; }
        }
        __shared__ float wsum_m[4], wsum_s[4];
        if (lane == 63) { wsum_m[wid] = im; wsum_s[wid] = is; }
        __syncthreads();
        float base_m = 0.f, base_s = 0.f;
        for (int wp = 0; wp < wid; ++wp) { base_m += wsum_m[wp]; base_s += wsum_s[wp]; }
        const float excl_m = base_m + (im - lm);
        const float excl_s = base_s + (is - ls);

        // second walk with running inclusive sum
        float* mcb = mc_ws + (size_t)b * S;
        float* rsb = rs_ws + (size_t)b * S;
        float run_m = alpha * h_mu + excl_m;
        float run_s = alpha * h_sg + excl_s;
        {
            float w = w0;
            for (int i = 0; i < CHUNK; ++i) {
                run_m += w * mub[s0 + i];
                run_s += w * sgb[s0 + i];
                mcb[s0 + i] = run_m;
                rsb[s0 + i] = 1.0f / fmaxf(run_s, EMA_EPS);
                w *= alpha;
            }
        }
        if (tid == 255) {
            float* h_new = out + (size_t)nrows * (size_t)D;
            h_new[b * 2 + 0] = run_m;
            h_new[b * 2 + 1] = fmaxf(run_s, EMA_EPS);
        }
    }

    grid.sync();

    // ---------------- Phase 3: normalize ----------------
    {
        const int n4     = nrows << d4_shift;      // total float4s
        const int stride = (int)(gridDim.x * blockDim.x);
        const int d4m    = d4 - 1;
        for (int gid = (int)(blockIdx.x * blockDim.x + threadIdx.x); gid < n4; gid += stride) {
            int row = gid >> d4_shift;
            int c4  = gid & d4m;
            float m  = mc_ws[row];
            float rs = rs_ws[row];
            float4 g  = ((const float4*)gamma)[c4];
            float4 bt = ((const float4*)beta)[c4];
            float4 xv = ((const float4*)x)[gid];
            float4 yv;
            yv.x = (xv.x - m) * rs * g.x + bt.x;
            yv.y = (xv.y - m) * rs * g.y + bt.y;
            yv.z = (xv.z - m) * rs * g.z + bt.z;
            yv.w = (xv.w - m) * rs * g.w + bt.w;
            ((float4*)out)[gid] = yv;
        }
    }
}

extern "C" void kernel_launch(void* const* d_in, const int* in_sizes, int n_in,
                              void* d_out, int out_size, void* d_ws, size_t ws_size,
                              hipStream_t stream) {
    const float* x           = (const float*)d_in[0];
    const float* h           = (const float*)d_in[1];
    const float* gamma       = (const float*)d_in[2];
    const float* beta        = (const float*)d_in[3];
    const float* alpha_logit = (const float*)d_in[4];
    float* out = (float*)d_out;
    float* ws  = (float*)d_ws;

    int D     = in_sizes[2];          // 512
    int B     = in_sizes[1] / 2;      // 8
    int total = in_sizes[0];          // B*S*D
    int S     = total / (B * D);      // 8192
    int d4_shift = __builtin_ctz(D / 4);

    void* args[] = { (void*)&x, (void*)&h, (void*)&gamma, (void*)&beta,
                     (void*)&alpha_logit, (void*)&out, (void*)&ws,
                     (void*)&B, (void*)&S, (void*)&d4_shift };

    // 1024 blocks x 256 thr = 4 blocks/CU; __launch_bounds__(256,4) guarantees
    // co-residency for the cooperative grid sync.
    hipLaunchCooperativeKernel((const void*)ema_fused_kernel,
                               dim3(1024), dim3(256), args, 0, stream);
}

// Round 3
// 260.971 us; speedup vs baseline: 1.8851x; 1.8851x over previous
//
#include <hip/hip_runtime.h>

#define EMA_EPS 1e-12f
#define TS 64          // s-rows per block in the scan+norm kernel

__device__ __forceinline__ float wave_reduce_sum(float v) {
    #pragma unroll
    for (int off = 32; off > 0; off >>= 1) v += __shfl_xor(v, off, 64);
    return v;
}

// ---------------------------------------------------------------------------
// K1: per-row mean / std (ddof=1). One 64-lane wave per row of D floats.
// ---------------------------------------------------------------------------
__global__ __launch_bounds__(256) void ema_stats_kernel(
    const float* __restrict__ x,
    float* __restrict__ mu, float* __restrict__ sigma,
    int nrows, int d4)
{
    int row  = (int)((blockIdx.x * blockDim.x + threadIdx.x) >> 6);
    int lane = threadIdx.x & 63;
    if (row >= nrows) return;

    const float4* xr = (const float4*)(x + (size_t)row * (size_t)(d4 * 4));
    float s = 0.f, sq = 0.f;
    for (int c = lane; c < d4; c += 64) {
        float4 a = xr[c];
        s  += a.x + a.y + a.z + a.w;
        sq += a.x*a.x + a.y*a.y + a.z*a.z + a.w*a.w;
    }
    s  = wave_reduce_sum(s);
    sq = wave_reduce_sum(sq);
    if (lane == 0) {
        int   n    = d4 * 4;
        float mean = s / (float)n;
        float var  = (sq - s * mean) / (float)(n - 1);
        mu[row]    = mean;
        sigma[row] = sqrtf(fmaxf(var, 0.0f));
    }
}

// ---------------------------------------------------------------------------
// K2: fused prefix-reduce + tile-scan + normalize.
// Grid = B * (S/TS) blocks, 256 threads. Block (b, tile) owns rows
// [s0, s0+TS) of batch b. Cross-block scan dependency is resolved by each
// block redundantly REDUCING the weighted prefix over [0, s0) — mu/sigma are
// tiny (L2/L3-resident), so the redundancy is ~free and no grid sync needed.
// ---------------------------------------------------------------------------
__global__ __launch_bounds__(256) void ema_scan_norm_kernel(
    const float* __restrict__ x,
    const float* __restrict__ mu, const float* __restrict__ sigma,
    const float* __restrict__ h, const float* __restrict__ alpha_logit,
    const float* __restrict__ gamma, const float* __restrict__ beta,
    float* __restrict__ out, int B, int S, int d4_shift)
{
    const int tiles = S / TS;
    const int b     = (int)blockIdx.x / tiles;
    const int tile  = (int)blockIdx.x % tiles;
    const int s0    = tile * TS;
    const int tid   = threadIdx.x;
    const int d4    = 1 << d4_shift;
    const int D     = d4 << 2;

    const float alpha = 1.0f / (1.0f + __expf(-alpha_logit[0]));
    const float oma   = 1.0f - alpha;
    const float l2a   = __log2f(alpha);

    const float* mub = mu    + (size_t)b * S;
    const float* sgb = sigma + (size_t)b * S;

    __shared__ float sh_wm[4], sh_ws[4];
    __shared__ float sh_pm, sh_ps;
    __shared__ float sh_m[TS], sh_r[TS];

    // ---- Phase A: weighted prefix reduction over [0, s0) ----
    float lm = 0.f, ls = 0.f;
    for (int t = tid; t < s0; t += 256) {
        float w = oma * exp2f((float)t * l2a);
        lm += w * mub[t];
        ls += w * sgb[t];
    }
    lm = wave_reduce_sum(lm);
    ls = wave_reduce_sum(ls);
    if ((tid & 63) == 0) { sh_wm[tid >> 6] = lm; sh_ws[tid >> 6] = ls; }
    __syncthreads();
    if (tid == 0) {
        sh_pm = sh_wm[0] + sh_wm[1] + sh_wm[2] + sh_wm[3];
        sh_ps = sh_ws[0] + sh_ws[1] + sh_ws[2] + sh_ws[3];
    }
    __syncthreads();

    // ---- Phase B: wave 0 scans the TS-row tile ----
    if (tid < 64) {
        const int lane = tid;
        float w  = oma * exp2f((float)(s0 + lane) * l2a);
        float vm = w * mub[s0 + lane];
        float vs = w * sgb[s0 + lane];
        #pragma unroll
        for (int off = 1; off < 64; off <<= 1) {
            float tm = __shfl_up(vm, off, 64);
            float tv = __shfl_up(vs, off, 64);
            if (lane >= off) { vm += tm; vs += tv; }
        }
        float run_m = alpha * h[b * 2 + 0] + sh_pm + vm;
        float run_s = fmaxf(alpha * h[b * 2 + 1] + sh_ps + vs, EMA_EPS);
        sh_m[lane] = run_m;
        sh_r[lane] = 1.0f / run_s;
        if (s0 + TS == S && lane == 63) {
            float* h_new = out + (size_t)B * S * D;
            h_new[b * 2 + 0] = run_m;
            h_new[b * 2 + 1] = run_s;
        }
    }
    __syncthreads();

    // ---- Phase C: normalize TS rows (x re-read is L3-warm) ----
    const size_t base = (size_t)(b * S + s0) << d4_shift;
    const float4* xb = (const float4*)x + base;
    float4*       yb = (float4*)out + base;
    const float4* g4 = (const float4*)gamma;
    const float4* b4 = (const float4*)beta;
    const int n4 = TS << d4_shift;
    for (int i = tid; i < n4; i += 256) {
        int r = i >> d4_shift;       // all 64 lanes of a wave share r (d4>=64)
        int c = i & (d4 - 1);
        float m  = sh_m[r];
        float rs = sh_r[r];
        float4 g  = g4[c];
        float4 bt = b4[c];
        float4 xv = xb[i];
        float4 yv;
        yv.x = (xv.x - m) * rs * g.x + bt.x;
        yv.y = (xv.y - m) * rs * g.y + bt.y;
        yv.z = (xv.z - m) * rs * g.z + bt.z;
        yv.w = (xv.w - m) * rs * g.w + bt.w;
        yb[i] = yv;
    }
}

extern "C" void kernel_launch(void* const* d_in, const int* in_sizes, int n_in,
                              void* d_out, int out_size, void* d_ws, size_t ws_size,
                              hipStream_t stream) {
    const float* x           = (const float*)d_in[0];
    const float* h           = (const float*)d_in[1];
    const float* gamma       = (const float*)d_in[2];
    const float* beta        = (const float*)d_in[3];
    const float* alpha_logit = (const float*)d_in[4];
    float* out = (float*)d_out;

    const int D     = in_sizes[2];          // 512
    const int B     = in_sizes[1] / 2;      // 8
    const int total = in_sizes[0];          // B*S*D
    const int S     = total / (B * D);      // 8192
    const int nrows = B * S;
    const int d4    = D / 4;
    const int d4_shift = __builtin_ctz(d4);

    float* mu_ws = (float*)d_ws;
    float* sg_ws = mu_ws + nrows;

    // K1: stats. One wave per row, 4 rows per 256-thread block.
    ema_stats_kernel<<<(nrows + 3) / 4, 256, 0, stream>>>(x, mu_ws, sg_ws, nrows, d4);

    // K2: fused prefix + scan + normalize. B*(S/TS) blocks.
    ema_scan_norm_kernel<<<B * (S / TS), 256, 0, stream>>>(
        x, mu_ws, sg_ws, h, alpha_logit, gamma, beta, out, B, S, d4_shift);
}